// Round 3
// baseline (787.983 us; speedup 1.0000x reference)
//
#include <hip/hip_runtime.h>
#include <math.h>

// Problem constants (fixed by reference)
#define B_TOT   256
#define N_TOT   2304
#define IN_DIM  8
#define NC      10      // NUM_CLASSES
#define OD      16      // OUT_DIM
#define CD      160     // NC*OD
#define RBIAS   0.1f

// Tiling
#define BTILE    64                      // b per block
#define VB       4                       // b per thread
#define NS       128                     // n-slices (grid.y)
#define NPB      (N_TOT / NS)            // 18 n per block
#define NTHREADS 320                     // (BTILE/VB)=16 p × 10 c × 2 dh
#define XR       (NPB * IN_DIM + 4)      // 148 floats per b row (16B-aligned stride)
#define CPAD     20                      // class stride in sh_W
#define WROW     (NC * CPAD)             // 200 floats per i-row
#define WBUF     (IN_DIM * WROW)         // 1600 floats per n
#define LROW     13                      // logit row pad
#define NREP     8                       // s_partial replicas

// One routing round. Thread (p,c,dh) owns b = b0+p*4+{0..3}, class c, d-half dh.
// x tile staged once to LDS; W double-buffered in LDS via register prefetch
// (one global load in flight per n-iter); 1 barrier per n.
// FIRST=1: cw = 1/10 exactly (softmax of zeros) — no S/logits at all.
// amdgpu_waves_per_eu(3,3): live set ~150 VGPRs; stop the allocator from
// occupancy-squeezing (R2: VGPR=84 -> scratch spill, WRITE_SIZE 163MB).
template <int FIRST>
__global__ __launch_bounds__(NTHREADS)
__attribute__((amdgpu_waves_per_eu(3, 3)))
void routing_round(
    const float* __restrict__ x,      // [B, N, 8]
    const float* __restrict__ W,      // [N, 8, 160]
    const float* __restrict__ S_acc,  // [B, 160]
    float* __restrict__ s_out)        // [NREP, B, 160]
{
    __shared__ float sh_x[BTILE * XR];         // 37.9 KB
    __shared__ float sh_W[2][WBUF];            // 12.8 KB
    __shared__ float sh_lg[2][BTILE * LROW];   // 6.7 KB

    const int tid = threadIdx.x;
    const int b0  = blockIdx.x * BTILE;
    const int n0  = blockIdx.y * NPB;
    const int p   = tid / 20;
    const int rem = tid - p * 20;
    const int c   = rem >> 1;
    const int dh  = rem & 1;
    const int bl0 = p * VB;                    // block-local b base

    // ---- stage x tile: [64 b][144 floats], coalesced float4
    {
        const int XT4 = BTILE * (NPB * IN_DIM / 4);   // 64*36 = 2304
        for (int k = tid; k < XT4; k += NTHREADS) {
            int bb   = k / (NPB * 2);
            int off4 = k - bb * (NPB * 2);
            float4 v = *(const float4*)(x + ((size_t)(b0 + bb) * N_TOT + n0) * IN_DIM + off4 * 4);
            *(float4*)(&sh_x[bb * XR + off4 * 4]) = v;
        }
    }

    // ---- S fragment: [4 b][8 d] (persistent, 32 regs)
    float S[VB][8];
    if (!FIRST) {
        #pragma unroll
        for (int j = 0; j < VB; j++) {
            const float4* sp = (const float4*)(S_acc + (size_t)(b0 + bl0 + j) * CD + c * OD + dh * 8);
            ((float4*)S[j])[0] = sp[0];
            ((float4*)S[j])[1] = sp[1];
        }
    }

    float acc[VB][8];
    #pragma unroll
    for (int j = 0; j < VB; j++)
        #pragma unroll
        for (int d = 0; d < 8; d++) acc[j][d] = 0.f;

    // ---- W staging map: thread stages floats [e, e+4) of the 1280-float n-row
    const int e  = tid * 4;
    const int wi = e / CD;
    const int wr = e - wi * CD;
    const int wc = wr >> 4;
    const int wd = wr & 15;
    const int wlds = wi * WROW + wc * CPAD + wd;
    const float* Wbase = W + (size_t)n0 * (IN_DIM * CD);

    {   // prologue: stage W row n0 into buffer 0
        float4 wv = *(const float4*)(Wbase + e);
        *(float4*)&sh_W[0][wlds] = wv;
    }
    __syncthreads();   // covers x tile + W buf 0

    for (int nn = 0; nn < NPB; nn++) {
        const int cur = nn & 1, nxt = cur ^ 1;

        // prefetch next W row into registers (hidden under this iter's compute)
        float4 wnext;
        if (nn + 1 < NPB)
            wnext = *(const float4*)(Wbase + (size_t)(nn + 1) * (IN_DIM * CD) + e);

        // u[4 b][8 d]; two i-halves to cap live x registers at 4 float4
        float u[VB][8];
        #pragma unroll
        for (int j = 0; j < VB; j++)
            #pragma unroll
            for (int d = 0; d < 8; d++) u[j][d] = 0.f;

        const float* wb = &sh_W[cur][c * CPAD + dh * 8];
        #pragma unroll
        for (int h = 0; h < 2; h++) {
            float4 xh[VB];
            #pragma unroll
            for (int j = 0; j < VB; j++)
                xh[j] = *(const float4*)(&sh_x[(bl0 + j) * XR + nn * IN_DIM + h * 4]);
            #pragma unroll
            for (int i = 0; i < 4; i++) {
                const int ig = h * 4 + i;
                float4 w0 = *(const float4*)(wb + ig * WROW);
                float4 w1 = *(const float4*)(wb + ig * WROW + 4);
                #pragma unroll
                for (int j = 0; j < VB; j++) {
                    float xv = ((const float*)&xh[j])[i];
                    u[j][0] += xv * w0.x;  u[j][1] += xv * w0.y;
                    u[j][2] += xv * w0.z;  u[j][3] += xv * w0.w;
                    u[j][4] += xv * w1.x;  u[j][5] += xv * w1.y;
                    u[j][6] += xv * w1.z;  u[j][7] += xv * w1.w;
                }
            }
        }

        float lg[VB];
        if (!FIRST) {
            #pragma unroll
            for (int j = 0; j < VB; j++) {
                float t = 0.f;
                #pragma unroll
                for (int d = 0; d < 8; d++) t += u[j][d] * S[j][d];
                t += __shfl_xor(t, 1, 64);      // partner d-half (adjacent lane)
                lg[j] = t;
            }
            if (dh == 0) {
                #pragma unroll
                for (int j = 0; j < VB; j++)
                    sh_lg[cur][(bl0 + j) * LROW + c] = lg[j];
            }
        }

        // stage next W into the other buffer (visible after barrier)
        if (nn + 1 < NPB)
            *(float4*)&sh_W[nxt][wlds] = wnext;

        __syncthreads();   // the ONLY barrier per n

        float cw[VB];
        if (!FIRST) {
            #pragma unroll
            for (int j = 0; j < VB; j++) {
                const float* row = &sh_lg[cur][(bl0 + j) * LROW];
                float m = row[0];
                #pragma unroll
                for (int k = 1; k < NC; k++) m = fmaxf(m, row[k]);
                float ssum = 0.f;
                #pragma unroll
                for (int k = 0; k < NC; k++) ssum += __expf(row[k] - m);
                cw[j] = __expf(lg[j] - m) / ssum;
            }
        } else {
            #pragma unroll
            for (int j = 0; j < VB; j++) cw[j] = 0.1f;
        }

        #pragma unroll
        for (int j = 0; j < VB; j++)
            #pragma unroll
            for (int d = 0; d < 8; d++) acc[j][d] += cw[j] * u[j][d];
    }

    // flush: 32 atomics/thread to one of 8 replicas (16 blocks contend/address)
    float* dst = s_out + (size_t)(blockIdx.y & (NREP - 1)) * (B_TOT * CD);
    #pragma unroll
    for (int j = 0; j < VB; j++) {
        float* row = dst + (size_t)(b0 + bl0 + j) * CD + c * OD + dh * 8;
        #pragma unroll
        for (int d = 0; d < 8; d++) atomicAdd(row + d, acc[j][d]);
    }
}

// Sums replicas + bias; folds into S_acc (rounds 0,1) or squashes to output (round 2).
__global__ __launch_bounds__(256) void fixup(
    const float* __restrict__ s_partial,   // [NREP, B, 160]
    float* __restrict__ S_acc,
    float* __restrict__ v_out,
    int is_final)
{
    int idx = blockIdx.x * 256 + threadIdx.x;   // 40960 = B*CD
    float s = RBIAS;
    #pragma unroll
    for (int r = 0; r < NREP; r++) s += s_partial[(size_t)r * (B_TOT * CD) + idx];
    if (!is_final) {
        S_acc[idx] += s;
    } else {
        float ss = s * s;   // squash over 16 consecutive lanes (one (b,c) row)
        #pragma unroll
        for (int off = 1; off < 16; off <<= 1)
            ss += __shfl_xor(ss, off, 64);
        float norm = sqrtf(ss);
        v_out[idx] = s * norm / (1.0f + ss);
    }
}

extern "C" void kernel_launch(void* const* d_in, const int* in_sizes, int n_in,
                              void* d_out, int out_size, void* d_ws, size_t ws_size,
                              hipStream_t stream) {
    const float* x = (const float*)d_in[0];   // [256,2304,8]
    const float* W = (const float*)d_in[1];   // [2304,8,160]
    float* out = (float*)d_out;               // [256,10,16]

    float* S_acc     = (float*)d_ws;                       // 40960 floats
    float* s_partial = S_acc + (size_t)B_TOT * CD;         // NREP * 40960 floats

    hipMemsetAsync(S_acc, 0, (size_t)B_TOT * CD * sizeof(float), stream);

    for (int r = 0; r < 3; r++) {
        hipMemsetAsync(s_partial, 0, (size_t)NREP * B_TOT * CD * sizeof(float), stream);
        if (r == 0)
            routing_round<1><<<dim3(B_TOT / BTILE, NS), NTHREADS, 0, stream>>>(x, W, S_acc, s_partial);
        else
            routing_round<0><<<dim3(B_TOT / BTILE, NS), NTHREADS, 0, stream>>>(x, W, S_acc, s_partial);
        fixup<<<(B_TOT * CD) / 256, 256, 0, stream>>>(s_partial, S_acc, out, r == 2);
    }
}

// Round 4
// 250.781 us; speedup vs baseline: 3.1421x; 3.1421x over previous
//
#include <hip/hip_runtime.h>
#include <math.h>

// Problem constants (fixed by reference)
#define B_TOT   256
#define N_TOT   2304
#define IN_DIM  8
#define NC      10      // NUM_CLASSES
#define OD      16      // OUT_DIM
#define CD      160     // NC*OD
#define RBIAS   0.1f

// Tiling
#define BTILE    64                      // b per block
#define VB       2                       // b per thread
#define NS       128                     // n-slices (grid.y)
#define NPB      (N_TOT / NS)            // 18 n per block
#define NTHREADS 640                     // 32 p × 10 c × 2 dh  (10 waves)
#define CPAD     20                      // class stride in sh_W
#define WROW     (NC * CPAD)             // 200 floats per i-row
#define WBUF     (IN_DIM * WROW)         // 1600 floats per n
#define LROW     13                      // logit row pad
#define NF4      (B_TOT * CD / 4)        // 10240 float4 per partial slab

// One routing round, NO atomics. Thread (p,c,dh) owns b=b0+2p+{0,1}, class c,
// d-half dh. W double-buffered in LDS (1 barrier/n); x straight from global
// (20 lanes share each row -> L1). Block writes its partial s tile to
// part[blockIdx.y] as plain stores; reduce_round sums the 128 slabs.
// FIRST=1: cw uniform -> acc holds plain sum of u; 0.1 scale applied in reduce.
template <int FIRST>
__global__ __launch_bounds__(NTHREADS) void routing_round(
    const float* __restrict__ x,      // [B, N, 8]
    const float* __restrict__ W,      // [N, 8, 160]
    const float* __restrict__ S_acc,  // [B, 160]
    float* __restrict__ part)         // [NS, B, 160]
{
    __shared__ float sh_W[2][WBUF];            // 12.8 KB
    __shared__ float sh_lg[2][BTILE * LROW];   // 6.7 KB

    const int tid = threadIdx.x;
    const int b0  = blockIdx.x * BTILE;
    const int n0  = blockIdx.y * NPB;
    const int p   = tid / 20;
    const int rem = tid - p * 20;
    const int c   = rem >> 1;
    const int dh  = rem & 1;
    const int bl0 = p * VB;

    // S fragment: [2 b][8 d] (persistent, 16 regs)
    float S[VB][8];
    if (!FIRST) {
        #pragma unroll
        for (int j = 0; j < VB; j++) {
            const float4* sp = (const float4*)(S_acc + (size_t)(b0 + bl0 + j) * CD + c * OD + dh * 8);
            ((float4*)S[j])[0] = sp[0];
            ((float4*)S[j])[1] = sp[1];
        }
    }

    float acc[VB][8];
    #pragma unroll
    for (int j = 0; j < VB; j++)
        #pragma unroll
        for (int d = 0; d < 8; d++) acc[j][d] = 0.f;

    // W staging: first 5 waves stage one float4 each (1280 floats per n-row)
    const bool stager = (tid < 320);
    const int e  = (tid & 255) + (tid & 256);           // = tid for tid<512; only tid<320 used
    const int e4 = tid * 4;
    const int wi = stager ? (e4 / CD) : 0;
    const int wr = stager ? (e4 - wi * CD) : 0;
    const int wc = wr >> 4;
    const int wd = wr & 15;
    const int wlds = wi * WROW + wc * CPAD + wd;
    const float* Wbase = W + (size_t)n0 * (IN_DIM * CD);

    if (stager) {
        float4 wv = *(const float4*)(Wbase + e4);
        *(float4*)&sh_W[0][wlds] = wv;
    }
    __syncthreads();

    for (int nn = 0; nn < NPB; nn++) {
        const int cur = nn & 1, nxt = cur ^ 1;

        float4 wnext;
        if (stager && nn + 1 < NPB)
            wnext = *(const float4*)(Wbase + (size_t)(nn + 1) * (IN_DIM * CD) + e4);

        float u[VB][8];
        #pragma unroll
        for (int j = 0; j < VB; j++)
            #pragma unroll
            for (int d = 0; d < 8; d++) u[j][d] = 0.f;

        const float* wb = &sh_W[cur][c * CPAD + dh * 8];
        #pragma unroll
        for (int h = 0; h < 2; h++) {           // i-halves cap live x at 2 float4
            float4 xh[VB];
            #pragma unroll
            for (int j = 0; j < VB; j++)
                xh[j] = *(const float4*)(x + ((size_t)(b0 + bl0 + j) * N_TOT + n0 + nn) * IN_DIM + h * 4);
            #pragma unroll
            for (int i = 0; i < 4; i++) {
                const int ig = h * 4 + i;
                float4 w0 = *(const float4*)(wb + ig * WROW);
                float4 w1 = *(const float4*)(wb + ig * WROW + 4);
                #pragma unroll
                for (int j = 0; j < VB; j++) {
                    float xv = ((const float*)&xh[j])[i];
                    u[j][0] += xv * w0.x;  u[j][1] += xv * w0.y;
                    u[j][2] += xv * w0.z;  u[j][3] += xv * w0.w;
                    u[j][4] += xv * w1.x;  u[j][5] += xv * w1.y;
                    u[j][6] += xv * w1.z;  u[j][7] += xv * w1.w;
                }
            }
        }

        float lg[VB];
        if (!FIRST) {
            #pragma unroll
            for (int j = 0; j < VB; j++) {
                float t = 0.f;
                #pragma unroll
                for (int d = 0; d < 8; d++) t += u[j][d] * S[j][d];
                t += __shfl_xor(t, 1, 64);      // partner d-half (adjacent lane)
                lg[j] = t;
            }
            if (dh == 0) {
                #pragma unroll
                for (int j = 0; j < VB; j++)
                    sh_lg[cur][(bl0 + j) * LROW + c] = lg[j];
            }
        }

        if (stager && nn + 1 < NPB)
            *(float4*)&sh_W[nxt][wlds] = wnext;

        __syncthreads();   // the ONLY barrier per n

        if (!FIRST) {
            #pragma unroll
            for (int j = 0; j < VB; j++) {
                const float* row = &sh_lg[cur][(bl0 + j) * LROW];
                float m = row[0];
                #pragma unroll
                for (int k = 1; k < NC; k++) m = fmaxf(m, row[k]);
                float ssum = 0.f;
                #pragma unroll
                for (int k = 0; k < NC; k++) ssum += __expf(row[k] - m);
                float cw = __expf(lg[j] - m) / ssum;
                #pragma unroll
                for (int d = 0; d < 8; d++) acc[j][d] += cw * u[j][d];
            }
        } else {
            #pragma unroll
            for (int j = 0; j < VB; j++)
                #pragma unroll
                for (int d = 0; d < 8; d++) acc[j][d] += u[j][d];   // cw folded in reduce
        }
    }

    // flush: plain coalesced stores to this block's private slab — NO atomics
    float* dst = part + ((size_t)blockIdx.y * B_TOT + (b0 + bl0)) * CD + c * OD + dh * 8;
    #pragma unroll
    for (int j = 0; j < VB; j++) {
        *(float4*)(dst + (size_t)j * CD)     = ((float4*)acc[j])[0];
        *(float4*)(dst + (size_t)j * CD + 4) = ((float4*)acc[j])[1];
    }
}

// Sums the NS partial slabs (+scale +bias); folds into S_acc (rounds 0,1)
// or squashes to output (round 2). One thread per float4 of [B,160].
__global__ __launch_bounds__(256) void reduce_round(
    const float* __restrict__ part,   // [NS, B, 160]
    float* __restrict__ S_acc,
    float* __restrict__ v_out,
    float scale, int is_final)
{
    int g = blockIdx.x * 256 + threadIdx.x;   // 0..NF4-1
    const float4* p4 = (const float4*)part;
    float sx = 0.f, sy = 0.f, sz = 0.f, sw = 0.f;
    for (int y = 0; y < NS; y++) {
        float4 t = p4[(size_t)y * NF4 + g];
        sx += t.x; sy += t.y; sz += t.z; sw += t.w;
    }
    sx = sx * scale + RBIAS;
    sy = sy * scale + RBIAS;
    sz = sz * scale + RBIAS;
    sw = sw * scale + RBIAS;
    if (!is_final) {
        float4* S4 = (float4*)S_acc;
        float4 o = S4[g];
        o.x += sx; o.y += sy; o.z += sz; o.w += sw;
        S4[g] = o;
    } else {
        // squash over 16 d = 4 consecutive lanes (one (b,c) row)
        float ss = sx * sx + sy * sy + sz * sz + sw * sw;
        ss += __shfl_xor(ss, 1, 64);
        ss += __shfl_xor(ss, 2, 64);
        float norm = sqrtf(ss);
        float k = norm / (1.0f + ss);
        float4 v = { sx * k, sy * k, sz * k, sw * k };
        ((float4*)v_out)[g] = v;
    }
}

extern "C" void kernel_launch(void* const* d_in, const int* in_sizes, int n_in,
                              void* d_out, int out_size, void* d_ws, size_t ws_size,
                              hipStream_t stream) {
    const float* x = (const float*)d_in[0];   // [256,2304,8]
    const float* W = (const float*)d_in[1];   // [2304,8,160]
    float* out = (float*)d_out;               // [256,10,16]

    float* S_acc = (float*)d_ws;                       // 40960 floats
    float* part  = S_acc + (size_t)B_TOT * CD;         // NS * 40960 floats (~21 MB)

    hipMemsetAsync(S_acc, 0, (size_t)B_TOT * CD * sizeof(float), stream);

    for (int r = 0; r < 3; r++) {
        if (r == 0)
            routing_round<1><<<dim3(B_TOT / BTILE, NS), NTHREADS, 0, stream>>>(x, W, S_acc, part);
        else
            routing_round<0><<<dim3(B_TOT / BTILE, NS), NTHREADS, 0, stream>>>(x, W, S_acc, part);
        reduce_round<<<NF4 / 256, 256, 0, stream>>>(part, S_acc, out,
                                                    r == 0 ? 0.1f : 1.0f, r == 2);
    }
}